// Round 20
// baseline (272.749 us; speedup 1.0000x reference)
//
#include <hip/hip_runtime.h>

#define BB 4
#define NN 16384
#define MM 512
#define CCH 256
#define KNN 24
#define EPSV 1e-5f

typedef unsigned short ushort_t;

__device__ __forceinline__ unsigned int pk_bf16(float a, float b) {
    unsigned int ua = __float_as_uint(a), ub = __float_as_uint(b);
    ua += 0x7FFFu + ((ua >> 16) & 1u);          // RNE to bf16
    ub += 0x7FFFu + ((ub >> 16) & 1u);
    return (ua >> 16) | (ub & 0xFFFF0000u);
}
__device__ __forceinline__ float lo_bf(unsigned int u) { return __uint_as_float(u << 16); }
__device__ __forceinline__ float hi_bf(unsigned int u) { return __uint_as_float(u & 0xFFFF0000u); }

// ---------------- K-1: pack x -> bf16 pairs (uint = 2 channels), lives in d_out ----------------
__global__ __launch_bounds__(256) void k_cvt(const float* __restrict__ x,
                                             unsigned int* __restrict__ xh) {
    int i = blockIdx.x * 256 + threadIdx.x;   // 8,388,608 float2s
    float2 v = ((const float2*)x)[i];
    xh[i] = pk_bf16(v.x, v.y);
}

// ---------------- K0: transpose fc_w (256x256) -> Wt[cin][cout] ----------------
__global__ __launch_bounds__(256) void k_wt(const float* __restrict__ W, float* __restrict__ Wt) {
    int i = blockIdx.x * 256 + threadIdx.x;   // 65536
    int co = i >> 8, ci = i & 255;
    Wt[(ci << 8) + co] = W[i];
}

// ---------------- K1: top-24, 4 lanes/node (r19-proven) ----------------
#define AE(K) "v_max_u32 v89, v88, " K "\n\tv_min_u32 " K ", v88, " K "\n\t"
#define AO(K) "v_max_u32 v88, v89, " K "\n\tv_min_u32 " K ", v89, " K "\n\t"
#define BE(K) "v_max_u32 v91, v90, " K "\n\tv_min_u32 " K ", v90, " K "\n\t"
#define BO(K) "v_max_u32 v90, v91, " K "\n\tv_min_u32 " K ", v91, " K "\n\t"
#define CE(K) "v_max_u32 v93, v92, " K "\n\tv_min_u32 " K ", v92, " K "\n\t"
#define CO(K) "v_max_u32 v92, v93, " K "\n\tv_min_u32 " K ", v93, " K "\n\t"
#define DE(K) "v_max_u32 v95, v94, " K "\n\tv_min_u32 " K ", v94, " K "\n\t"
#define DO_(K) "v_max_u32 v94, v95, " K "\n\tv_min_u32 " K ", v95, " K "\n\t"
#define CHAIN4 \
    AE("v64") \
    AO("v65") BE("v64") \
    AE("v66") BO("v65") CE("v64") \
    AO("v67") BE("v66") CO("v65") DE("v64") \
    AE("v68") BO("v67") CE("v66") DO_("v65") \
    AO("v69") BE("v68") CO("v67") DE("v66") \
    AE("v70") BO("v69") CE("v68") DO_("v67") \
    AO("v71") BE("v70") CO("v69") DE("v68") \
    AE("v72") BO("v71") CE("v70") DO_("v69") \
    AO("v73") BE("v72") CO("v71") DE("v70") \
    AE("v74") BO("v73") CE("v72") DO_("v71") \
    AO("v75") BE("v74") CO("v73") DE("v72") \
    AE("v76") BO("v75") CE("v74") DO_("v73") \
    AO("v77") BE("v76") CO("v75") DE("v74") \
    AE("v78") BO("v77") CE("v76") DO_("v75") \
    AO("v79") BE("v78") CO("v77") DE("v76") \
    AE("v80") BO("v79") CE("v78") DO_("v77") \
    AO("v81") BE("v80") CO("v79") DE("v78") \
    AE("v82") BO("v81") CE("v80") DO_("v79") \
    AO("v83") BE("v82") CO("v81") DE("v80") \
    AE("v84") BO("v83") CE("v82") DO_("v81") \
    AO("v85") BE("v84") CO("v83") DE("v82") \
    AE("v86") BO("v85") CE("v84") DO_("v83") \
    AO("v87") BE("v86") CO("v85") DE("v84") \
              BO("v87") CE("v86") DO_("v85") \
                        CO("v87") DE("v86") \
                                  DO_("v87")
#define CEU(A, B) { unsigned int lo_ = min(A, B); B = max(A, B); A = lo_; }
#define MRG(MI, KJ, K23MJ, K12PJ, K11MJ) \
    { unsigned int sA_ = (unsigned int)__shfl_xor((int)(K23MJ), 32); \
      unsigned int sB_ = (unsigned int)__shfl_xor((int)(K12PJ), 32); \
      MI = ((half == 0) ? min((KJ), sA_) : min(sB_, (K11MJ))) & 511u; }
__global__ __launch_bounds__(256, 2) void k_topk(const float* __restrict__ coords,
                                                 const float* __restrict__ anchors,
                                                 ushort_t* __restrict__ idx_out,
                                                 int* __restrict__ histT) {
    __shared__ float4 alds[MM + 4];  // padded: +1 float4 per 128 anchors
    __shared__ int    hist[MM];      // 2 KB
    int tid = threadIdx.x;
    int blk = blockIdx.x;           // 1024 blocks: 256 per batch
    int b  = blk >> 8;
    int g  = blk & 255;             // 64-node group id within batch
    int n0 = g << 6;
    int lane = tid & 63;
    int w = tid >> 6;               // wave 0..3, 16 nodes each
    int q = (lane >> 4) & 3;        // quarter: anchors [q*128, q*128+128)
    int half = lane >> 5;           // 0: quarters {0,1}; 1: {2,3}
    bool qa = ((lane >> 4) & 1) == 0;   // active lanes (q0, q2)
    int n = n0 + (w << 4) + (lane & 15);

    for (int m = tid; m < MM; m += 256) {
        float x_ = anchors[(b * MM + m) * 3 + 0];
        float y_ = anchors[(b * MM + m) * 3 + 1];
        float z_ = anchors[(b * MM + m) * 3 + 2];
        alds[m + (m >> 7)] = make_float4(x_, y_, z_, x_ * x_ + y_ * y_ + z_ * z_);
        hist[m] = 0;
    }
    __syncthreads();

    float cx = coords[(b * NN + n) * 3 + 0];
    float cy = coords[(b * NN + n) * 3 + 1];
    float cz = coords[(b * NN + n) * 3 + 2];
    float cn2 = cx * cx + cy * cy + cz * cz;

    unsigned int k0 = 0xFFFFFFFFu, k1 = 0xFFFFFFFFu, k2 = 0xFFFFFFFFu, k3 = 0xFFFFFFFFu,
                 k4 = 0xFFFFFFFFu, k5 = 0xFFFFFFFFu, k6 = 0xFFFFFFFFu, k7 = 0xFFFFFFFFu,
                 k8 = 0xFFFFFFFFu, k9 = 0xFFFFFFFFu, k10 = 0xFFFFFFFFu, k11 = 0xFFFFFFFFu,
                 k12 = 0xFFFFFFFFu, k13 = 0xFFFFFFFFu, k14 = 0xFFFFFFFFu, k15 = 0xFFFFFFFFu,
                 k16 = 0xFFFFFFFFu, k17 = 0xFFFFFFFFu, k18 = 0xFFFFFFFFu, k19 = 0xFFFFFFFFu,
                 k20 = 0xFFFFFFFFu, k21 = 0xFFFFFFFFu, k22 = 0xFFFFFFFFu, k23 = 0xFFFFFFFFu;

    int qbase = (q << 7) + q;       // padded base: quarter q starts at bank 4q
    float4 a0 = alds[qbase + 0];
    float4 a1 = alds[qbase + 1];
    float4 a2 = alds[qbase + 2];
    float4 a3 = alds[qbase + 3];
    float4 a4 = alds[qbase + 4];
    float4 a5 = alds[qbase + 5];
    float4 a6 = alds[qbase + 6];
    float4 a7 = alds[qbase + 7];
    for (int mm = 0; mm < 16; ++mm) {
        int nxt = (8 * mm + 8) & 127;
        float4 p0 = alds[qbase + nxt + 0];      // prefetch before the asm
        float4 p1 = alds[qbase + nxt + 1];
        float4 p2 = alds[qbase + nxt + 2];
        float4 p3 = alds[qbase + nxt + 3];
        float4 p4 = alds[qbase + nxt + 4];
        float4 p5 = alds[qbase + nxt + 5];
        float4 p6 = alds[qbase + nxt + 6];
        float4 p7 = alds[qbase + nxt + 7];
        float cd0 = cn2 + a0.w - 2.0f * (cx * a0.x + cy * a0.y + cz * a0.z);
        float cd1 = cn2 + a1.w - 2.0f * (cx * a1.x + cy * a1.y + cz * a1.z);
        float cd2 = cn2 + a2.w - 2.0f * (cx * a2.x + cy * a2.y + cz * a2.z);
        float cd3 = cn2 + a3.w - 2.0f * (cx * a3.x + cy * a3.y + cz * a3.z);
        float cd4 = cn2 + a4.w - 2.0f * (cx * a4.x + cy * a4.y + cz * a4.z);
        float cd5 = cn2 + a5.w - 2.0f * (cx * a5.x + cy * a5.y + cz * a5.z);
        float cd6 = cn2 + a6.w - 2.0f * (cx * a6.x + cy * a6.y + cz * a6.z);
        float cd7 = cn2 + a7.w - 2.0f * (cx * a7.x + cy * a7.y + cz * a7.z);
        int id0 = (q << 7) + 8 * mm;
        unsigned int cA = ((__float_as_uint(cd0) ^ 0x80000000u) & 0xFFFFFE00u) | (unsigned)(id0 + 0);
        unsigned int cB = ((__float_as_uint(cd1) ^ 0x80000000u) & 0xFFFFFE00u) | (unsigned)(id0 + 1);
        unsigned int cC = ((__float_as_uint(cd2) ^ 0x80000000u) & 0xFFFFFE00u) | (unsigned)(id0 + 2);
        unsigned int cD = ((__float_as_uint(cd3) ^ 0x80000000u) & 0xFFFFFE00u) | (unsigned)(id0 + 3);
        unsigned int cE = ((__float_as_uint(cd4) ^ 0x80000000u) & 0xFFFFFE00u) | (unsigned)(id0 + 4);
        unsigned int cF = ((__float_as_uint(cd5) ^ 0x80000000u) & 0xFFFFFE00u) | (unsigned)(id0 + 5);
        unsigned int cG = ((__float_as_uint(cd6) ^ 0x80000000u) & 0xFFFFFE00u) | (unsigned)(id0 + 6);
        unsigned int cH = ((__float_as_uint(cd7) ^ 0x80000000u) & 0xFFFFFE00u) | (unsigned)(id0 + 7);
        asm volatile(
            CHAIN4
            "v_mov_b32 v88, v96\n\t"
            "v_mov_b32 v90, v98\n\t"
            "v_mov_b32 v92, v100\n\t"
            "v_mov_b32 v94, v102\n\t"
            CHAIN4
            : "+{v64}"(k0),  "+{v65}"(k1),  "+{v66}"(k2),  "+{v67}"(k3),
              "+{v68}"(k4),  "+{v69}"(k5),  "+{v70}"(k6),  "+{v71}"(k7),
              "+{v72}"(k8),  "+{v73}"(k9),  "+{v74}"(k10), "+{v75}"(k11),
              "+{v76}"(k12), "+{v77}"(k13), "+{v78}"(k14), "+{v79}"(k15),
              "+{v80}"(k16), "+{v81}"(k17), "+{v82}"(k18), "+{v83}"(k19),
              "+{v84}"(k20), "+{v85}"(k21), "+{v86}"(k22), "+{v87}"(k23),
              "+{v88}"(cA), "+{v90}"(cB), "+{v92}"(cC), "+{v94}"(cD),
              "+{v96}"(cE), "+{v98}"(cF), "+{v100}"(cG), "+{v102}"(cH)
            :
            : "v89", "v91", "v93", "v95");
        a0 = p0; a1 = p1; a2 = p2; a3 = p3;
        a4 = p4; a5 = p5; a6 = p6; a7 = p7;
    }

    // ---- level-1 merge across lane^16 (quarter pairs {0,1} and {2,3}) ----
    unsigned int r0  = (unsigned)__shfl_xor((int)k0, 16);
    unsigned int r1  = (unsigned)__shfl_xor((int)k1, 16);
    unsigned int r2  = (unsigned)__shfl_xor((int)k2, 16);
    unsigned int r3  = (unsigned)__shfl_xor((int)k3, 16);
    unsigned int r4  = (unsigned)__shfl_xor((int)k4, 16);
    unsigned int r5  = (unsigned)__shfl_xor((int)k5, 16);
    unsigned int r6  = (unsigned)__shfl_xor((int)k6, 16);
    unsigned int r7  = (unsigned)__shfl_xor((int)k7, 16);
    unsigned int r8  = (unsigned)__shfl_xor((int)k8, 16);
    unsigned int r9  = (unsigned)__shfl_xor((int)k9, 16);
    unsigned int r10 = (unsigned)__shfl_xor((int)k10, 16);
    unsigned int r11 = (unsigned)__shfl_xor((int)k11, 16);
    unsigned int r12 = (unsigned)__shfl_xor((int)k12, 16);
    unsigned int r13 = (unsigned)__shfl_xor((int)k13, 16);
    unsigned int r14 = (unsigned)__shfl_xor((int)k14, 16);
    unsigned int r15 = (unsigned)__shfl_xor((int)k15, 16);
    unsigned int r16_ = (unsigned)__shfl_xor((int)k16, 16);
    unsigned int r17 = (unsigned)__shfl_xor((int)k17, 16);
    unsigned int r18 = (unsigned)__shfl_xor((int)k18, 16);
    unsigned int r19 = (unsigned)__shfl_xor((int)k19, 16);
    unsigned int r20 = (unsigned)__shfl_xor((int)k20, 16);
    unsigned int r21 = (unsigned)__shfl_xor((int)k21, 16);
    unsigned int r22 = (unsigned)__shfl_xor((int)k22, 16);
    unsigned int r23 = (unsigned)__shfl_xor((int)k23, 16);
    unsigned int L0  = qa ? min(k0,  r23) : min(r0,  k23);
    unsigned int L1  = qa ? min(k1,  r22) : min(r1,  k22);
    unsigned int L2  = qa ? min(k2,  r21) : min(r2,  k21);
    unsigned int L3  = qa ? min(k3,  r20) : min(r3,  k20);
    unsigned int L4  = qa ? min(k4,  r19) : min(r4,  k19);
    unsigned int L5  = qa ? min(k5,  r18) : min(r5,  k18);
    unsigned int L6  = qa ? min(k6,  r17) : min(r6,  k17);
    unsigned int L7  = qa ? min(k7,  r16_) : min(r7,  k16);
    unsigned int L8  = qa ? min(k8,  r15) : min(r8,  k15);
    unsigned int L9  = qa ? min(k9,  r14) : min(r9,  k14);
    unsigned int L10 = qa ? min(k10, r13) : min(r10, k13);
    unsigned int L11 = qa ? min(k11, r12) : min(r11, k12);
    unsigned int L12 = qa ? min(k12, r11) : min(r12, k11);
    unsigned int L13 = qa ? min(k13, r10) : min(r13, k10);
    unsigned int L14 = qa ? min(k14, r9)  : min(r14, k9);
    unsigned int L15 = qa ? min(k15, r8)  : min(r15, k8);
    unsigned int L16 = qa ? min(k16, r7)  : min(r16_, k7);
    unsigned int L17 = qa ? min(k17, r6)  : min(r17, k6);
    unsigned int L18 = qa ? min(k18, r5)  : min(r18, k5);
    unsigned int L19 = qa ? min(k19, r4)  : min(r19, k4);
    unsigned int L20 = qa ? min(k20, r3)  : min(r20, k3);
    unsigned int L21 = qa ? min(k21, r2)  : min(r21, k2);
    unsigned int L22 = qa ? min(k22, r1)  : min(r22, k1);
    unsigned int L23 = qa ? min(k23, r0)  : min(r23, k0);
    // 52-CE bitonic merge (mountain + conceptual -inf pad)
    CEU(L0, L16) CEU(L1, L17) CEU(L2, L18) CEU(L3, L19)
    CEU(L4, L20) CEU(L5, L21) CEU(L6, L22) CEU(L7, L23)
    CEU(L8, L16) CEU(L9, L17) CEU(L10, L18) CEU(L11, L19)
    CEU(L12, L20) CEU(L13, L21) CEU(L14, L22) CEU(L15, L23)
    CEU(L0, L4) CEU(L1, L5) CEU(L2, L6) CEU(L3, L7)
    CEU(L8, L12) CEU(L9, L13) CEU(L10, L14) CEU(L11, L15)
    CEU(L16, L20) CEU(L17, L21) CEU(L18, L22) CEU(L19, L23)
    CEU(L0, L2) CEU(L1, L3) CEU(L4, L6) CEU(L5, L7)
    CEU(L8, L10) CEU(L9, L11) CEU(L12, L14) CEU(L13, L15)
    CEU(L16, L18) CEU(L17, L19) CEU(L20, L22) CEU(L21, L23)
    CEU(L0, L1) CEU(L2, L3) CEU(L4, L5) CEU(L6, L7)
    CEU(L8, L9) CEU(L10, L11) CEU(L12, L13) CEU(L14, L15)
    CEU(L16, L17) CEU(L18, L19) CEU(L20, L21) CEU(L22, L23)

    // ---- level-2: cross-lane merge via shfl_xor(32) ----
    unsigned int Mi0, Mi1, Mi2, Mi3, Mi4, Mi5, Mi6, Mi7, Mi8, Mi9, Mi10, Mi11;
    MRG(Mi0,  L0,  L23, L12, L11)
    MRG(Mi1,  L1,  L22, L13, L10)
    MRG(Mi2,  L2,  L21, L14, L9)
    MRG(Mi3,  L3,  L20, L15, L8)
    MRG(Mi4,  L4,  L19, L16, L7)
    MRG(Mi5,  L5,  L18, L17, L6)
    MRG(Mi6,  L6,  L17, L18, L5)
    MRG(Mi7,  L7,  L16, L19, L4)
    MRG(Mi8,  L8,  L15, L20, L3)
    MRG(Mi9,  L9,  L14, L21, L2)
    MRG(Mi10, L10, L13, L22, L1)
    MRG(Mi11, L11, L12, L23, L0)

    if (qa) {   // q0 (half 0) and q2 (half 1) lanes carry the result
        atomicAdd(&hist[Mi0], 1);  atomicAdd(&hist[Mi1], 1);
        atomicAdd(&hist[Mi2], 1);  atomicAdd(&hist[Mi3], 1);
        atomicAdd(&hist[Mi4], 1);  atomicAdd(&hist[Mi5], 1);
        atomicAdd(&hist[Mi6], 1);  atomicAdd(&hist[Mi7], 1);
        atomicAdd(&hist[Mi8], 1);  atomicAdd(&hist[Mi9], 1);
        atomicAdd(&hist[Mi10], 1); atomicAdd(&hist[Mi11], 1);

        unsigned int* ob = (unsigned int*)(idx_out + (size_t)(b * NN + n) * KNN + half * 12);
        ob[0] = Mi0 | (Mi1 << 16);
        ob[1] = Mi2 | (Mi3 << 16);
        ob[2] = Mi4 | (Mi5 << 16);
        ob[3] = Mi6 | (Mi7 << 16);
        ob[4] = Mi8 | (Mi9 << 16);
        ob[5] = Mi10 | (Mi11 << 16);
    }

    __syncthreads();
    // counting-sort input: histT[((b*512)+m)*256 + g]
    for (int m = tid; m < MM; m += 256)
        histT[((((b << 9) + m)) << 8) + g] = hist[m];
}

// ---------------- K1b: per-edge scan over the 256 groups -> posT, deg ----------------
__global__ __launch_bounds__(64) void k_scan(const int* __restrict__ histT,
                                             int* __restrict__ posT,
                                             int* __restrict__ deg) {
    int e = blockIdx.x;             // 2048 = (b<<9)+m
    int t = threadIdx.x;
    int4 v = ((const int4*)(histT + (e << 8)))[t];   // 4 consecutive g per lane
    int s = v.x + v.y + v.z + v.w;
    int inc = s;
    #pragma unroll
    for (int off = 1; off < 64; off <<= 1) {
        int u = __shfl_up(inc, off);
        if (t >= off) inc += u;
    }
    int excl = inc - s;
    int4 o;
    o.x = excl; o.y = excl + v.x; o.z = o.y + v.y; o.w = o.z + v.z;
    ((int4*)(posT + (e << 8)))[t] = o;
    if (t == 63) deg[e] = inc;
}

// ---------------- K2a: exclusive prefix sum of deg (2048) -> offs ----------------
__global__ __launch_bounds__(256) void k_offsets(const int* __restrict__ deg,
                                                 int* __restrict__ offs) {
    __shared__ int part[256];
    int t = threadIdx.x;
    int v[8];
    int s = 0;
    #pragma unroll
    for (int j = 0; j < 8; ++j) { v[j] = deg[t * 8 + j]; s += v[j]; }
    part[t] = s;
    __syncthreads();
    for (int off = 1; off < 256; off <<= 1) {
        int val = (t >= off) ? part[t - off] : 0;
        __syncthreads();
        part[t] += val;
        __syncthreads();
    }
    int excl = part[t] - s;
    #pragma unroll
    for (int j = 0; j < 8; ++j) { offs[t * 8 + j] = excl; excl += v[j]; }
}

// ---------------- K2b: counting-sort scatter (LDS cursors, no global atomics) ----------------
__global__ __launch_bounds__(256) void k_fill2(const unsigned int* __restrict__ idxu,
                                               const int* __restrict__ posT,
                                               const int* __restrict__ offs,
                                               ushort_t* __restrict__ list) {
    __shared__ int pos[MM];
    __shared__ unsigned int ebuf[768];      // 64 nodes x 12 packed uints
    int tid = threadIdx.x;
    int blk = blockIdx.x;                   // 1024 = (b<<8)+g
    int b = blk >> 8, g = blk & 255;
    int n0 = g << 6;

    for (int m = tid; m < MM; m += 256) {
        int e = (b << 9) + m;
        pos[m] = offs[e] + posT[(e << 8) + g];
    }
    for (int i = tid; i < 768; i += 256)
        ebuf[i] = idxu[(size_t)(b * NN + n0) * 12 + i];
    __syncthreads();

    for (int i = tid; i < 768; i += 256) {
        unsigned int u = ebuf[i];
        int node = n0 + (i / 12);
        int p0 = atomicAdd(&pos[u & 0xFFFFu], 1);
        list[p0] = (ushort_t)node;
        int p1 = atomicAdd(&pos[u >> 16], 1);
        list[p1] = (ushort_t)node;
    }
}

// ---------------- K3a: gather quarters (uint2 = 4 channels/load) -> S[e][256] ----------------
__global__ __launch_bounds__(256) void k_edge2a(const unsigned int* __restrict__ xh,
                                                const ushort_t* __restrict__ list,
                                                const int* __restrict__ offs,
                                                const int* __restrict__ deg,
                                                float* __restrict__ S) {
    __shared__ ushort_t nl[256];
    __shared__ float red[16][64];           // 4 KB: [row-split][channel-in-quarter]
    int tid = threadIdx.x;
    int bi = blockIdx.x;                    // 8192
    int r = bi >> 12;                       // round 0/1
    int grp = (bi & 7) | (r << 3);          // 16 groups
    int b = grp & 3;                        // batch
    int q = grp >> 2;                       // channel quarter (16 uint2)
    int e = (b << 9) | ((bi >> 3) & 511);
    int d = deg[e];
    int o = offs[e];
    int cp = tid & 15, rs = tid >> 4;       // uint2-in-quarter, 16-way row split
    const uint2* xb = (const uint2*)(xh + ((size_t)b << 21)) + (q << 4);

    float s0 = 0.f, s1 = 0.f, s2 = 0.f, s3 = 0.f;
    float t0 = 0.f, t1 = 0.f, t2 = 0.f, t3 = 0.f;
    for (int base2 = 0; base2 < d; base2 += 256) {
        int cnt = min(256, d - base2);
        if (tid < cnt) nl[tid] = list[(size_t)o + base2 + tid];
        __syncthreads();
        int i = 0;
        for (; i + 31 < cnt; i += 32) {
            uint2 u0 = xb[((size_t)nl[i + rs] << 6) + cp];
            uint2 u1 = xb[((size_t)nl[i + 16 + rs] << 6) + cp];
            s0 += lo_bf(u0.x); s1 += hi_bf(u0.x); s2 += lo_bf(u0.y); s3 += hi_bf(u0.y);
            t0 += lo_bf(u1.x); t1 += hi_bf(u1.x); t2 += lo_bf(u1.y); t3 += hi_bf(u1.y);
        }
        for (; i + 15 < cnt; i += 16) {
            uint2 u = xb[((size_t)nl[i + rs] << 6) + cp];
            s0 += lo_bf(u.x); s1 += hi_bf(u.x); s2 += lo_bf(u.y); s3 += hi_bf(u.y);
        }
        if (i + rs < cnt) {
            uint2 u = xb[((size_t)nl[i + rs] << 6) + cp];
            t0 += lo_bf(u.x); t1 += hi_bf(u.x); t2 += lo_bf(u.y); t3 += hi_bf(u.y);
        }
        __syncthreads();
    }
    *(float4*)&red[rs][4 * cp] = make_float4(s0 + t0, s1 + t1, s2 + t2, s3 + t3);
    __syncthreads();
    if (tid < 64) {
        float s = 0.f;
        #pragma unroll
        for (int j = 0; j < 16; ++j) s += red[j][tid];
        S[((size_t)e << 8) + (q << 6) + tid] = s;
    }
}

// ---------------- K3b: E' = ((S*inv_e)@W^T + b*(deg>0)) / 24, bf16 out ----------------
__global__ __launch_bounds__(256) void k_edge2b(const float* __restrict__ S,
                                                const int* __restrict__ deg,
                                                const float* __restrict__ Wt,
                                                const float* __restrict__ fcb,
                                                unsigned int* __restrict__ Eph) {
    __shared__ float srow[CCH];
    __shared__ float rrow[CCH];
    int tid = threadIdx.x;
    int e = blockIdx.x;                     // 2048
    int d = deg[e];
    float inv = (d > 0) ? (1.0f / (float)d) : 0.0f;
    srow[tid] = S[((size_t)e << 8) + tid] * inv;
    __syncthreads();

    float c0 = (d > 0) ? fcb[tid] : 0.0f;
    float c1 = 0.f, c2 = 0.f, c3 = 0.f;
    #pragma unroll 4
    for (int ci = 0; ci < CCH; ci += 4) {
        c0 = fmaf(srow[ci + 0], Wt[((ci + 0) << 8) + tid], c0);
        c1 = fmaf(srow[ci + 1], Wt[((ci + 1) << 8) + tid], c1);
        c2 = fmaf(srow[ci + 2], Wt[((ci + 2) << 8) + tid], c2);
        c3 = fmaf(srow[ci + 3], Wt[((ci + 3) << 8) + tid], c3);
    }
    rrow[tid] = ((c0 + c1) + (c2 + c3)) * (1.0f / 24.0f);
    __syncthreads();
    if (tid < 128) Eph[((size_t)e << 7) + tid] = pk_bf16(rrow[2 * tid], rrow[2 * tid + 1]);
}

// ---------------- K4: out = H@E' + x, 16-node tiles for 2x occupancy ----------------
// r19 post-mortem: tile[32][257] (33KB) capped the CU at 4 blocks = 38% occupancy;
// the L2 E-gather is latency-bound. 16-node tiles (18KB LDS) -> 8 blocks/CU = cap.
__global__ __launch_bounds__(256) void k_gather(const float* __restrict__ x,
                                                const unsigned int* __restrict__ idxu,
                                                const unsigned int* __restrict__ Eph,
                                                float* __restrict__ out,
                                                float* __restrict__ bn1,
                                                float* __restrict__ bn2) {
    __shared__ int   it[16 * KNN];          // 384 ints
    __shared__ float tile[16][CCH + 1];     // 16 x 257 = 16.4 KB
    int tid = threadIdx.x;
    int blk = blockIdx.x;                   // 4096: b * 1024 node-chunks
    int b = blk >> 10;
    int n0 = (blk & 1023) << 4;             // 16 nodes
    int cp = tid & 63, rs = tid >> 6;       // uint2 channel-pair, 4-way node split

    for (int i = tid; i < 16 * 12; i += 256) {           // 192 packed uints
        unsigned int u = idxu[(size_t)(b * NN + n0) * 12 + i];
        it[2 * i] = u & 0xFFFF;
        it[2 * i + 1] = u >> 16;
    }
    __syncthreads();

    const uint2* Eb = (const uint2*)(Eph + ((size_t)(b * MM) << 7));
    for (int j2 = 0; j2 < 4; ++j2) {
        int j = 4 * j2 + rs;
        int n = n0 + j;
        const int* itj = &it[j * KNN];
        float a0 = 0.f, a1 = 0.f, a2 = 0.f, a3 = 0.f;
        float b0 = 0.f, b1 = 0.f, b2 = 0.f, b3 = 0.f;
        #pragma unroll
        for (int k = 0; k < KNN; k += 2) {
            uint2 u0 = Eb[((size_t)itj[k + 0] << 6) + cp];
            uint2 u1 = Eb[((size_t)itj[k + 1] << 6) + cp];
            a0 += lo_bf(u0.x); a1 += hi_bf(u0.x); a2 += lo_bf(u0.y); a3 += hi_bf(u0.y);
            b0 += lo_bf(u1.x); b1 += hi_bf(u1.x); b2 += lo_bf(u1.y); b3 += hi_bf(u1.y);
        }
        float4 xv = ((const float4*)(x + (((size_t)(b * NN + n)) << 8)))[cp];
        tile[j][4 * cp + 0] = xv.x + a0 + b0;
        tile[j][4 * cp + 1] = xv.y + a1 + b1;
        tile[j][4 * cp + 2] = xv.z + a2 + b2;
        tile[j][4 * cp + 3] = xv.w + a3 + b3;
    }
    __syncthreads();

    float sum = 0.f, ss = 0.f;
    #pragma unroll 4
    for (int j = 0; j < 16; ++j) {
        float v = tile[j][tid];
        sum += v; ss += v * v;
    }
    bn1[(size_t)blk * 256 + tid] = sum;
    bn2[(size_t)blk * 256 + tid] = ss;

    for (int i = tid; i < CCH * 16; i += 256) {
        int c2 = i >> 4, j2 = i & 15;
        out[(((size_t)(b * CCH + c2)) << 14) + n0 + j2] = tile[j2][c2];
    }
}

// ---------------- K5: finalize BN stats -> a[c], bb[c] ----------------
__global__ __launch_bounds__(256) void k_stats(const float* __restrict__ bn1,
                                               const float* __restrict__ bn2,
                                               const float* __restrict__ gamma,
                                               const float* __restrict__ beta,
                                               float* __restrict__ ab) {
    __shared__ float r1[256], r2[256];
    int c = blockIdx.x;
    int t = threadIdx.x;
    float s1 = 0.f, s2 = 0.f;
    for (int i = t; i < 4096; i += 256) {
        s1 += bn1[i * 256 + c];
        s2 += bn2[i * 256 + c];
    }
    r1[t] = s1; r2[t] = s2;
    __syncthreads();
    for (int o = 128; o > 0; o >>= 1) {
        if (t < o) { r1[t] += r1[t + o]; r2[t] += r2[t + o]; }
        __syncthreads();
    }
    if (t == 0) {
        float mean = r1[0] * (1.0f / 65536.0f);
        float var  = r2[0] * (1.0f / 65536.0f) - mean * mean;
        float istd = rsqrtf(var + EPSV);
        float a = gamma[c] * istd;
        ab[c] = a;
        ab[CCH + c] = beta[c] - mean * a;
    }
}

// ---------------- K6: in-place normalize + SiLU ----------------
__global__ __launch_bounds__(256) void k_silu(float* __restrict__ out,
                                              const float* __restrict__ ab) {
    int i = blockIdx.x * 256 + threadIdx.x;     // float4 index, 4194304 total
    int c = (i >> 12) & 255;
    float a = ab[c], bb = ab[CCH + c];
    float4 v = ((float4*)out)[i];
    float t0 = a * v.x + bb;
    float t1 = a * v.y + bb;
    float t2 = a * v.z + bb;
    float t3 = a * v.w + bb;
    v.x = t0 / (1.0f + __expf(-t0));
    v.y = t1 / (1.0f + __expf(-t1));
    v.z = t2 / (1.0f + __expf(-t2));
    v.w = t3 / (1.0f + __expf(-t3));
    ((float4*)out)[i] = v;
}

extern "C" void kernel_launch(void* const* d_in, const int* in_sizes, int n_in,
                              void* d_out, int out_size, void* d_ws, size_t ws_size,
                              hipStream_t stream) {
    (void)in_sizes; (void)n_in; (void)out_size; (void)ws_size;
    const float* x       = (const float*)d_in[0];
    const float* coords  = (const float*)d_in[1];
    const float* anchors = (const float*)d_in[2];
    const float* fcw     = (const float*)d_in[3];
    const float* fcb     = (const float*)d_in[4];
    const float* gamma   = (const float*)d_in[5];
    const float* beta    = (const float*)d_in[6];
    float* out = (float*)d_out;

    // bf16-packed x lives in d_out (33.5 MB of 67 MB); dead before k_gather
    // overwrites d_out. ws footprint 22.3 MB (< round-1-proven 29.6 MB).
    unsigned int* xh = (unsigned int*)d_out;

    char* ws = (char*)d_ws;
    ushort_t*     ws_idx   = (ushort_t*)    (ws + 0);          // 3,145,728 B
    int*          ws_deg   = (int*)         (ws + 3145728);    //     8,192 B
    int*          ws_offs  = (int*)         (ws + 3153920);    //     8,192 B
    ushort_t*     ws_list  = (ushort_t*)    (ws + 3162112);    // 3,145,728 B
    int*          ws_histT = (int*)         (ws + 6307840);    // 2,097,152 B
    int*          ws_posT  = (int*)         (ws + 8404992);    // 2,097,152 B
    unsigned int* ws_eph   = (unsigned int*)(ws + 10502144);   // 1,048,576 B
    float*        ws_S     = (float*)       (ws + 11550720);   // 2,097,152 B
    float*        ws_wt    = (float*)       (ws + 13647872);   //   262,144 B
    float*        ws_bn1   = (float*)       (ws + 13910016);   // 4,194,304 B
    float*        ws_bn2   = (float*)       (ws + 18104320);   // 4,194,304 B
    float*        ws_ab    = (float*)       (ws + 22298624);   //     2,048 B

    hipLaunchKernelGGL(k_cvt,     dim3(32768), dim3(256), 0, stream, x, xh);
    hipLaunchKernelGGL(k_wt,      dim3(256),   dim3(256), 0, stream, fcw, ws_wt);
    hipLaunchKernelGGL(k_topk,    dim3(1024),  dim3(256), 0, stream, coords, anchors, ws_idx, ws_histT);
    hipLaunchKernelGGL(k_scan,    dim3(2048),  dim3(64),  0, stream, ws_histT, ws_posT, ws_deg);
    hipLaunchKernelGGL(k_offsets, dim3(1),     dim3(256), 0, stream, ws_deg, ws_offs);
    hipLaunchKernelGGL(k_fill2,   dim3(1024),  dim3(256), 0, stream, (const unsigned int*)ws_idx, ws_posT, ws_offs, ws_list);
    hipLaunchKernelGGL(k_edge2a,  dim3(8192),  dim3(256), 0, stream, xh, ws_list, ws_offs, ws_deg, ws_S);
    hipLaunchKernelGGL(k_edge2b,  dim3(2048),  dim3(256), 0, stream, ws_S, ws_deg, ws_wt, fcb, ws_eph);
    hipLaunchKernelGGL(k_gather,  dim3(4096),  dim3(256), 0, stream, x, (const unsigned int*)ws_idx, ws_eph, out, ws_bn1, ws_bn2);
    hipLaunchKernelGGL(k_stats,   dim3(256),   dim3(256), 0, stream, ws_bn1, ws_bn2, gamma, beta, ws_ab);
    hipLaunchKernelGGL(k_silu,    dim3(16384), dim3(256), 0, stream, out, ws_ab);
}

// Round 21
// 256.318 us; speedup vs baseline: 1.0641x; 1.0641x over previous
//
#include <hip/hip_runtime.h>

#define BB 4
#define NN 16384
#define MM 512
#define CCH 256
#define KNN 24
#define EPSV 1e-5f

typedef unsigned short ushort_t;

__device__ __forceinline__ unsigned int pk_bf16(float a, float b) {
    unsigned int ua = __float_as_uint(a), ub = __float_as_uint(b);
    ua += 0x7FFFu + ((ua >> 16) & 1u);          // RNE to bf16
    ub += 0x7FFFu + ((ub >> 16) & 1u);
    return (ua >> 16) | (ub & 0xFFFF0000u);
}
__device__ __forceinline__ float lo_bf(unsigned int u) { return __uint_as_float(u << 16); }
__device__ __forceinline__ float hi_bf(unsigned int u) { return __uint_as_float(u & 0xFFFF0000u); }

// ---------------- K-1: pack x -> bf16 pairs (uint = 2 channels), lives in d_out ----------------
__global__ __launch_bounds__(256) void k_cvt(const float* __restrict__ x,
                                             unsigned int* __restrict__ xh) {
    int i = blockIdx.x * 256 + threadIdx.x;   // 8,388,608 float2s
    float2 v = ((const float2*)x)[i];
    xh[i] = pk_bf16(v.x, v.y);
}

// ---------------- K0: transpose fc_w (256x256) -> Wt[cin][cout] ----------------
__global__ __launch_bounds__(256) void k_wt(const float* __restrict__ W, float* __restrict__ Wt) {
    int i = blockIdx.x * 256 + threadIdx.x;   // 65536
    int co = i >> 8, ci = i & 255;
    Wt[(ci << 8) + co] = W[i];
}

// ---------------- K1: top-24, 4 lanes/node (r19/r20-proven, padded alds) ----------------
#define AE(K) "v_max_u32 v89, v88, " K "\n\tv_min_u32 " K ", v88, " K "\n\t"
#define AO(K) "v_max_u32 v88, v89, " K "\n\tv_min_u32 " K ", v89, " K "\n\t"
#define BE(K) "v_max_u32 v91, v90, " K "\n\tv_min_u32 " K ", v90, " K "\n\t"
#define BO(K) "v_max_u32 v90, v91, " K "\n\tv_min_u32 " K ", v91, " K "\n\t"
#define CE(K) "v_max_u32 v93, v92, " K "\n\tv_min_u32 " K ", v92, " K "\n\t"
#define CO(K) "v_max_u32 v92, v93, " K "\n\tv_min_u32 " K ", v93, " K "\n\t"
#define DE(K) "v_max_u32 v95, v94, " K "\n\tv_min_u32 " K ", v94, " K "\n\t"
#define DO_(K) "v_max_u32 v94, v95, " K "\n\tv_min_u32 " K ", v95, " K "\n\t"
#define CHAIN4 \
    AE("v64") \
    AO("v65") BE("v64") \
    AE("v66") BO("v65") CE("v64") \
    AO("v67") BE("v66") CO("v65") DE("v64") \
    AE("v68") BO("v67") CE("v66") DO_("v65") \
    AO("v69") BE("v68") CO("v67") DE("v66") \
    AE("v70") BO("v69") CE("v68") DO_("v67") \
    AO("v71") BE("v70") CO("v69") DE("v68") \
    AE("v72") BO("v71") CE("v70") DO_("v69") \
    AO("v73") BE("v72") CO("v71") DE("v70") \
    AE("v74") BO("v73") CE("v72") DO_("v71") \
    AO("v75") BE("v74") CO("v73") DE("v72") \
    AE("v76") BO("v75") CE("v74") DO_("v73") \
    AO("v77") BE("v76") CO("v75") DE("v74") \
    AE("v78") BO("v77") CE("v76") DO_("v75") \
    AO("v79") BE("v78") CO("v77") DE("v76") \
    AE("v80") BO("v79") CE("v78") DO_("v77") \
    AO("v81") BE("v80") CO("v79") DE("v78") \
    AE("v82") BO("v81") CE("v80") DO_("v79") \
    AO("v83") BE("v82") CO("v81") DE("v80") \
    AE("v84") BO("v83") CE("v82") DO_("v81") \
    AO("v85") BE("v84") CO("v83") DE("v82") \
    AE("v86") BO("v85") CE("v84") DO_("v83") \
    AO("v87") BE("v86") CO("v85") DE("v84") \
              BO("v87") CE("v86") DO_("v85") \
                        CO("v87") DE("v86") \
                                  DO_("v87")
#define CEU(A, B) { unsigned int lo_ = min(A, B); B = max(A, B); A = lo_; }
#define MRG(MI, KJ, K23MJ, K12PJ, K11MJ) \
    { unsigned int sA_ = (unsigned int)__shfl_xor((int)(K23MJ), 32); \
      unsigned int sB_ = (unsigned int)__shfl_xor((int)(K12PJ), 32); \
      MI = ((half == 0) ? min((KJ), sA_) : min(sB_, (K11MJ))) & 511u; }
__global__ __launch_bounds__(256, 2) void k_topk(const float* __restrict__ coords,
                                                 const float* __restrict__ anchors,
                                                 ushort_t* __restrict__ idx_out,
                                                 int* __restrict__ histT) {
    __shared__ float4 alds[MM + 4];  // padded: +1 float4 per 128 anchors
    __shared__ int    hist[MM];      // 2 KB
    int tid = threadIdx.x;
    int blk = blockIdx.x;           // 1024 blocks: 256 per batch
    int b  = blk >> 8;
    int g  = blk & 255;             // 64-node group id within batch
    int n0 = g << 6;
    int lane = tid & 63;
    int w = tid >> 6;               // wave 0..3, 16 nodes each
    int q = (lane >> 4) & 3;        // quarter: anchors [q*128, q*128+128)
    int half = lane >> 5;           // 0: quarters {0,1}; 1: {2,3}
    bool qa = ((lane >> 4) & 1) == 0;   // active lanes (q0, q2)
    int n = n0 + (w << 4) + (lane & 15);

    for (int m = tid; m < MM; m += 256) {
        float x_ = anchors[(b * MM + m) * 3 + 0];
        float y_ = anchors[(b * MM + m) * 3 + 1];
        float z_ = anchors[(b * MM + m) * 3 + 2];
        alds[m + (m >> 7)] = make_float4(x_, y_, z_, x_ * x_ + y_ * y_ + z_ * z_);
        hist[m] = 0;
    }
    __syncthreads();

    float cx = coords[(b * NN + n) * 3 + 0];
    float cy = coords[(b * NN + n) * 3 + 1];
    float cz = coords[(b * NN + n) * 3 + 2];
    float cn2 = cx * cx + cy * cy + cz * cz;

    unsigned int k0 = 0xFFFFFFFFu, k1 = 0xFFFFFFFFu, k2 = 0xFFFFFFFFu, k3 = 0xFFFFFFFFu,
                 k4 = 0xFFFFFFFFu, k5 = 0xFFFFFFFFu, k6 = 0xFFFFFFFFu, k7 = 0xFFFFFFFFu,
                 k8 = 0xFFFFFFFFu, k9 = 0xFFFFFFFFu, k10 = 0xFFFFFFFFu, k11 = 0xFFFFFFFFu,
                 k12 = 0xFFFFFFFFu, k13 = 0xFFFFFFFFu, k14 = 0xFFFFFFFFu, k15 = 0xFFFFFFFFu,
                 k16 = 0xFFFFFFFFu, k17 = 0xFFFFFFFFu, k18 = 0xFFFFFFFFu, k19 = 0xFFFFFFFFu,
                 k20 = 0xFFFFFFFFu, k21 = 0xFFFFFFFFu, k22 = 0xFFFFFFFFu, k23 = 0xFFFFFFFFu;

    int qbase = (q << 7) + q;       // padded base: quarter q starts at bank 4q
    float4 a0 = alds[qbase + 0];
    float4 a1 = alds[qbase + 1];
    float4 a2 = alds[qbase + 2];
    float4 a3 = alds[qbase + 3];
    float4 a4 = alds[qbase + 4];
    float4 a5 = alds[qbase + 5];
    float4 a6 = alds[qbase + 6];
    float4 a7 = alds[qbase + 7];
    for (int mm = 0; mm < 16; ++mm) {
        int nxt = (8 * mm + 8) & 127;
        float4 p0 = alds[qbase + nxt + 0];      // prefetch before the asm
        float4 p1 = alds[qbase + nxt + 1];
        float4 p2 = alds[qbase + nxt + 2];
        float4 p3 = alds[qbase + nxt + 3];
        float4 p4 = alds[qbase + nxt + 4];
        float4 p5 = alds[qbase + nxt + 5];
        float4 p6 = alds[qbase + nxt + 6];
        float4 p7 = alds[qbase + nxt + 7];
        float cd0 = cn2 + a0.w - 2.0f * (cx * a0.x + cy * a0.y + cz * a0.z);
        float cd1 = cn2 + a1.w - 2.0f * (cx * a1.x + cy * a1.y + cz * a1.z);
        float cd2 = cn2 + a2.w - 2.0f * (cx * a2.x + cy * a2.y + cz * a2.z);
        float cd3 = cn2 + a3.w - 2.0f * (cx * a3.x + cy * a3.y + cz * a3.z);
        float cd4 = cn2 + a4.w - 2.0f * (cx * a4.x + cy * a4.y + cz * a4.z);
        float cd5 = cn2 + a5.w - 2.0f * (cx * a5.x + cy * a5.y + cz * a5.z);
        float cd6 = cn2 + a6.w - 2.0f * (cx * a6.x + cy * a6.y + cz * a6.z);
        float cd7 = cn2 + a7.w - 2.0f * (cx * a7.x + cy * a7.y + cz * a7.z);
        int id0 = (q << 7) + 8 * mm;
        unsigned int cA = ((__float_as_uint(cd0) ^ 0x80000000u) & 0xFFFFFE00u) | (unsigned)(id0 + 0);
        unsigned int cB = ((__float_as_uint(cd1) ^ 0x80000000u) & 0xFFFFFE00u) | (unsigned)(id0 + 1);
        unsigned int cC = ((__float_as_uint(cd2) ^ 0x80000000u) & 0xFFFFFE00u) | (unsigned)(id0 + 2);
        unsigned int cD = ((__float_as_uint(cd3) ^ 0x80000000u) & 0xFFFFFE00u) | (unsigned)(id0 + 3);
        unsigned int cE = ((__float_as_uint(cd4) ^ 0x80000000u) & 0xFFFFFE00u) | (unsigned)(id0 + 4);
        unsigned int cF = ((__float_as_uint(cd5) ^ 0x80000000u) & 0xFFFFFE00u) | (unsigned)(id0 + 5);
        unsigned int cG = ((__float_as_uint(cd6) ^ 0x80000000u) & 0xFFFFFE00u) | (unsigned)(id0 + 6);
        unsigned int cH = ((__float_as_uint(cd7) ^ 0x80000000u) & 0xFFFFFE00u) | (unsigned)(id0 + 7);
        asm volatile(
            CHAIN4
            "v_mov_b32 v88, v96\n\t"
            "v_mov_b32 v90, v98\n\t"
            "v_mov_b32 v92, v100\n\t"
            "v_mov_b32 v94, v102\n\t"
            CHAIN4
            : "+{v64}"(k0),  "+{v65}"(k1),  "+{v66}"(k2),  "+{v67}"(k3),
              "+{v68}"(k4),  "+{v69}"(k5),  "+{v70}"(k6),  "+{v71}"(k7),
              "+{v72}"(k8),  "+{v73}"(k9),  "+{v74}"(k10), "+{v75}"(k11),
              "+{v76}"(k12), "+{v77}"(k13), "+{v78}"(k14), "+{v79}"(k15),
              "+{v80}"(k16), "+{v81}"(k17), "+{v82}"(k18), "+{v83}"(k19),
              "+{v84}"(k20), "+{v85}"(k21), "+{v86}"(k22), "+{v87}"(k23),
              "+{v88}"(cA), "+{v90}"(cB), "+{v92}"(cC), "+{v94}"(cD),
              "+{v96}"(cE), "+{v98}"(cF), "+{v100}"(cG), "+{v102}"(cH)
            :
            : "v89", "v91", "v93", "v95");
        a0 = p0; a1 = p1; a2 = p2; a3 = p3;
        a4 = p4; a5 = p5; a6 = p6; a7 = p7;
    }

    // ---- level-1 merge across lane^16 (quarter pairs {0,1} and {2,3}) ----
    unsigned int r0  = (unsigned)__shfl_xor((int)k0, 16);
    unsigned int r1  = (unsigned)__shfl_xor((int)k1, 16);
    unsigned int r2  = (unsigned)__shfl_xor((int)k2, 16);
    unsigned int r3  = (unsigned)__shfl_xor((int)k3, 16);
    unsigned int r4  = (unsigned)__shfl_xor((int)k4, 16);
    unsigned int r5  = (unsigned)__shfl_xor((int)k5, 16);
    unsigned int r6  = (unsigned)__shfl_xor((int)k6, 16);
    unsigned int r7  = (unsigned)__shfl_xor((int)k7, 16);
    unsigned int r8  = (unsigned)__shfl_xor((int)k8, 16);
    unsigned int r9  = (unsigned)__shfl_xor((int)k9, 16);
    unsigned int r10 = (unsigned)__shfl_xor((int)k10, 16);
    unsigned int r11 = (unsigned)__shfl_xor((int)k11, 16);
    unsigned int r12 = (unsigned)__shfl_xor((int)k12, 16);
    unsigned int r13 = (unsigned)__shfl_xor((int)k13, 16);
    unsigned int r14 = (unsigned)__shfl_xor((int)k14, 16);
    unsigned int r15 = (unsigned)__shfl_xor((int)k15, 16);
    unsigned int r16_ = (unsigned)__shfl_xor((int)k16, 16);
    unsigned int r17 = (unsigned)__shfl_xor((int)k17, 16);
    unsigned int r18 = (unsigned)__shfl_xor((int)k18, 16);
    unsigned int r19 = (unsigned)__shfl_xor((int)k19, 16);
    unsigned int r20 = (unsigned)__shfl_xor((int)k20, 16);
    unsigned int r21 = (unsigned)__shfl_xor((int)k21, 16);
    unsigned int r22 = (unsigned)__shfl_xor((int)k22, 16);
    unsigned int r23 = (unsigned)__shfl_xor((int)k23, 16);
    unsigned int L0  = qa ? min(k0,  r23) : min(r0,  k23);
    unsigned int L1  = qa ? min(k1,  r22) : min(r1,  k22);
    unsigned int L2  = qa ? min(k2,  r21) : min(r2,  k21);
    unsigned int L3  = qa ? min(k3,  r20) : min(r3,  k20);
    unsigned int L4  = qa ? min(k4,  r19) : min(r4,  k19);
    unsigned int L5  = qa ? min(k5,  r18) : min(r5,  k18);
    unsigned int L6  = qa ? min(k6,  r17) : min(r6,  k17);
    unsigned int L7  = qa ? min(k7,  r16_) : min(r7,  k16);
    unsigned int L8  = qa ? min(k8,  r15) : min(r8,  k15);
    unsigned int L9  = qa ? min(k9,  r14) : min(r9,  k14);
    unsigned int L10 = qa ? min(k10, r13) : min(r10, k13);
    unsigned int L11 = qa ? min(k11, r12) : min(r11, k12);
    unsigned int L12 = qa ? min(k12, r11) : min(r12, k11);
    unsigned int L13 = qa ? min(k13, r10) : min(r13, k10);
    unsigned int L14 = qa ? min(k14, r9)  : min(r14, k9);
    unsigned int L15 = qa ? min(k15, r8)  : min(r15, k8);
    unsigned int L16 = qa ? min(k16, r7)  : min(r16_, k7);
    unsigned int L17 = qa ? min(k17, r6)  : min(r17, k6);
    unsigned int L18 = qa ? min(k18, r5)  : min(r18, k5);
    unsigned int L19 = qa ? min(k19, r4)  : min(r19, k4);
    unsigned int L20 = qa ? min(k20, r3)  : min(r20, k3);
    unsigned int L21 = qa ? min(k21, r2)  : min(r21, k2);
    unsigned int L22 = qa ? min(k22, r1)  : min(r22, k1);
    unsigned int L23 = qa ? min(k23, r0)  : min(r23, k0);
    // 52-CE bitonic merge (mountain + conceptual -inf pad)
    CEU(L0, L16) CEU(L1, L17) CEU(L2, L18) CEU(L3, L19)
    CEU(L4, L20) CEU(L5, L21) CEU(L6, L22) CEU(L7, L23)
    CEU(L8, L16) CEU(L9, L17) CEU(L10, L18) CEU(L11, L19)
    CEU(L12, L20) CEU(L13, L21) CEU(L14, L22) CEU(L15, L23)
    CEU(L0, L4) CEU(L1, L5) CEU(L2, L6) CEU(L3, L7)
    CEU(L8, L12) CEU(L9, L13) CEU(L10, L14) CEU(L11, L15)
    CEU(L16, L20) CEU(L17, L21) CEU(L18, L22) CEU(L19, L23)
    CEU(L0, L2) CEU(L1, L3) CEU(L4, L6) CEU(L5, L7)
    CEU(L8, L10) CEU(L9, L11) CEU(L12, L14) CEU(L13, L15)
    CEU(L16, L18) CEU(L17, L19) CEU(L20, L22) CEU(L21, L23)
    CEU(L0, L1) CEU(L2, L3) CEU(L4, L5) CEU(L6, L7)
    CEU(L8, L9) CEU(L10, L11) CEU(L12, L13) CEU(L14, L15)
    CEU(L16, L17) CEU(L18, L19) CEU(L20, L21) CEU(L22, L23)

    // ---- level-2: cross-lane merge via shfl_xor(32) ----
    unsigned int Mi0, Mi1, Mi2, Mi3, Mi4, Mi5, Mi6, Mi7, Mi8, Mi9, Mi10, Mi11;
    MRG(Mi0,  L0,  L23, L12, L11)
    MRG(Mi1,  L1,  L22, L13, L10)
    MRG(Mi2,  L2,  L21, L14, L9)
    MRG(Mi3,  L3,  L20, L15, L8)
    MRG(Mi4,  L4,  L19, L16, L7)
    MRG(Mi5,  L5,  L18, L17, L6)
    MRG(Mi6,  L6,  L17, L18, L5)
    MRG(Mi7,  L7,  L16, L19, L4)
    MRG(Mi8,  L8,  L15, L20, L3)
    MRG(Mi9,  L9,  L14, L21, L2)
    MRG(Mi10, L10, L13, L22, L1)
    MRG(Mi11, L11, L12, L23, L0)

    if (qa) {   // q0 (half 0) and q2 (half 1) lanes carry the result
        atomicAdd(&hist[Mi0], 1);  atomicAdd(&hist[Mi1], 1);
        atomicAdd(&hist[Mi2], 1);  atomicAdd(&hist[Mi3], 1);
        atomicAdd(&hist[Mi4], 1);  atomicAdd(&hist[Mi5], 1);
        atomicAdd(&hist[Mi6], 1);  atomicAdd(&hist[Mi7], 1);
        atomicAdd(&hist[Mi8], 1);  atomicAdd(&hist[Mi9], 1);
        atomicAdd(&hist[Mi10], 1); atomicAdd(&hist[Mi11], 1);

        unsigned int* ob = (unsigned int*)(idx_out + (size_t)(b * NN + n) * KNN + half * 12);
        ob[0] = Mi0 | (Mi1 << 16);
        ob[1] = Mi2 | (Mi3 << 16);
        ob[2] = Mi4 | (Mi5 << 16);
        ob[3] = Mi6 | (Mi7 << 16);
        ob[4] = Mi8 | (Mi9 << 16);
        ob[5] = Mi10 | (Mi11 << 16);
    }

    __syncthreads();
    // counting-sort input: histT[((b*512)+m)*256 + g]
    for (int m = tid; m < MM; m += 256)
        histT[((((b << 9) + m)) << 8) + g] = hist[m];
}

// ---------------- K1b: per-edge scan over the 256 groups -> posT, deg ----------------
__global__ __launch_bounds__(64) void k_scan(const int* __restrict__ histT,
                                             int* __restrict__ posT,
                                             int* __restrict__ deg) {
    int e = blockIdx.x;             // 2048 = (b<<9)+m
    int t = threadIdx.x;
    int4 v = ((const int4*)(histT + (e << 8)))[t];   // 4 consecutive g per lane
    int s = v.x + v.y + v.z + v.w;
    int inc = s;
    #pragma unroll
    for (int off = 1; off < 64; off <<= 1) {
        int u = __shfl_up(inc, off);
        if (t >= off) inc += u;
    }
    int excl = inc - s;
    int4 o;
    o.x = excl; o.y = excl + v.x; o.z = o.y + v.y; o.w = o.z + v.z;
    ((int4*)(posT + (e << 8)))[t] = o;
    if (t == 63) deg[e] = inc;
}

// ---------------- K2a: exclusive prefix sum of deg (2048) -> offs ----------------
__global__ __launch_bounds__(256) void k_offsets(const int* __restrict__ deg,
                                                 int* __restrict__ offs) {
    __shared__ int part[256];
    int t = threadIdx.x;
    int v[8];
    int s = 0;
    #pragma unroll
    for (int j = 0; j < 8; ++j) { v[j] = deg[t * 8 + j]; s += v[j]; }
    part[t] = s;
    __syncthreads();
    for (int off = 1; off < 256; off <<= 1) {
        int val = (t >= off) ? part[t - off] : 0;
        __syncthreads();
        part[t] += val;
        __syncthreads();
    }
    int excl = part[t] - s;
    #pragma unroll
    for (int j = 0; j < 8; ++j) { offs[t * 8 + j] = excl; excl += v[j]; }
}

// ---------------- K2b: counting-sort scatter (LDS cursors, no global atomics) ----------------
__global__ __launch_bounds__(256) void k_fill2(const unsigned int* __restrict__ idxu,
                                               const int* __restrict__ posT,
                                               const int* __restrict__ offs,
                                               ushort_t* __restrict__ list) {
    __shared__ int pos[MM];
    __shared__ unsigned int ebuf[768];      // 64 nodes x 12 packed uints
    int tid = threadIdx.x;
    int blk = blockIdx.x;                   // 1024 = (b<<8)+g
    int b = blk >> 8, g = blk & 255;
    int n0 = g << 6;

    for (int m = tid; m < MM; m += 256) {
        int e = (b << 9) + m;
        pos[m] = offs[e] + posT[(e << 8) + g];
    }
    for (int i = tid; i < 768; i += 256)
        ebuf[i] = idxu[(size_t)(b * NN + n0) * 12 + i];
    __syncthreads();

    for (int i = tid; i < 768; i += 256) {
        unsigned int u = ebuf[i];
        int node = n0 + (i / 12);
        int p0 = atomicAdd(&pos[u & 0xFFFFu], 1);
        list[p0] = (ushort_t)node;
        int p1 = atomicAdd(&pos[u >> 16], 1);
        list[p1] = (ushort_t)node;
    }
}

// ---------------- K3a: gather quarters (uint2 = 4 channels/load) -> S[e][256] ----------------
__global__ __launch_bounds__(256) void k_edge2a(const unsigned int* __restrict__ xh,
                                                const ushort_t* __restrict__ list,
                                                const int* __restrict__ offs,
                                                const int* __restrict__ deg,
                                                float* __restrict__ S) {
    __shared__ ushort_t nl[256];
    __shared__ float red[16][64];           // 4 KB: [row-split][channel-in-quarter]
    int tid = threadIdx.x;
    int bi = blockIdx.x;                    // 8192
    int r = bi >> 12;                       // round 0/1
    int grp = (bi & 7) | (r << 3);          // 16 groups
    int b = grp & 3;                        // batch
    int q = grp >> 2;                       // channel quarter (16 uint2)
    int e = (b << 9) | ((bi >> 3) & 511);
    int d = deg[e];
    int o = offs[e];
    int cp = tid & 15, rs = tid >> 4;       // uint2-in-quarter, 16-way row split
    const uint2* xb = (const uint2*)(xh + ((size_t)b << 21)) + (q << 4);

    float s0 = 0.f, s1 = 0.f, s2 = 0.f, s3 = 0.f;
    float t0 = 0.f, t1 = 0.f, t2 = 0.f, t3 = 0.f;
    for (int base2 = 0; base2 < d; base2 += 256) {
        int cnt = min(256, d - base2);
        if (tid < cnt) nl[tid] = list[(size_t)o + base2 + tid];
        __syncthreads();
        int i = 0;
        for (; i + 31 < cnt; i += 32) {
            uint2 u0 = xb[((size_t)nl[i + rs] << 6) + cp];
            uint2 u1 = xb[((size_t)nl[i + 16 + rs] << 6) + cp];
            s0 += lo_bf(u0.x); s1 += hi_bf(u0.x); s2 += lo_bf(u0.y); s3 += hi_bf(u0.y);
            t0 += lo_bf(u1.x); t1 += hi_bf(u1.x); t2 += lo_bf(u1.y); t3 += hi_bf(u1.y);
        }
        for (; i + 15 < cnt; i += 16) {
            uint2 u = xb[((size_t)nl[i + rs] << 6) + cp];
            s0 += lo_bf(u.x); s1 += hi_bf(u.x); s2 += lo_bf(u.y); s3 += hi_bf(u.y);
        }
        if (i + rs < cnt) {
            uint2 u = xb[((size_t)nl[i + rs] << 6) + cp];
            t0 += lo_bf(u.x); t1 += hi_bf(u.x); t2 += lo_bf(u.y); t3 += hi_bf(u.y);
        }
        __syncthreads();
    }
    *(float4*)&red[rs][4 * cp] = make_float4(s0 + t0, s1 + t1, s2 + t2, s3 + t3);
    __syncthreads();
    if (tid < 64) {
        float s = 0.f;
        #pragma unroll
        for (int j = 0; j < 16; ++j) s += red[j][tid];
        S[((size_t)e << 8) + (q << 6) + tid] = s;
    }
}

// ---------------- K3b: E' = ((S*inv_e)@W^T + b*(deg>0)) / 24, bf16 out ----------------
__global__ __launch_bounds__(256) void k_edge2b(const float* __restrict__ S,
                                                const int* __restrict__ deg,
                                                const float* __restrict__ Wt,
                                                const float* __restrict__ fcb,
                                                unsigned int* __restrict__ Eph) {
    __shared__ float srow[CCH];
    __shared__ float rrow[CCH];
    int tid = threadIdx.x;
    int e = blockIdx.x;                     // 2048
    int d = deg[e];
    float inv = (d > 0) ? (1.0f / (float)d) : 0.0f;
    srow[tid] = S[((size_t)e << 8) + tid] * inv;
    __syncthreads();

    float c0 = (d > 0) ? fcb[tid] : 0.0f;
    float c1 = 0.f, c2 = 0.f, c3 = 0.f;
    #pragma unroll 4
    for (int ci = 0; ci < CCH; ci += 4) {
        c0 = fmaf(srow[ci + 0], Wt[((ci + 0) << 8) + tid], c0);
        c1 = fmaf(srow[ci + 1], Wt[((ci + 1) << 8) + tid], c1);
        c2 = fmaf(srow[ci + 2], Wt[((ci + 2) << 8) + tid], c2);
        c3 = fmaf(srow[ci + 3], Wt[((ci + 3) << 8) + tid], c3);
    }
    rrow[tid] = ((c0 + c1) + (c2 + c3)) * (1.0f / 24.0f);
    __syncthreads();
    if (tid < 128) Eph[((size_t)e << 7) + tid] = pk_bf16(rrow[2 * tid], rrow[2 * tid + 1]);
}

// ---------------- K4: out = H@E' + x (r18-proven: scalar dword, 32-node tile) ----------------
__global__ __launch_bounds__(256) void k_gather(const float* __restrict__ x,
                                                const unsigned int* __restrict__ idxu,
                                                const unsigned int* __restrict__ Eph,
                                                float* __restrict__ out,
                                                float* __restrict__ bn1,
                                                float* __restrict__ bn2) {
    __shared__ int   it[32 * KNN];          // 768 ints
    __shared__ float tile[32][CCH + 1];     // 32 x 257 = 32.9 KB
    int tid = threadIdx.x;
    int blk = blockIdx.x;                   // 2048: b * 512 node-chunks
    int b = blk >> 9;
    int n0 = (blk & 511) << 5;              // 32 nodes
    int cp = tid & 127, rs = tid >> 7;

    for (int i = tid; i < 32 * 12; i += 256) {           // 384 packed uints
        unsigned int u = idxu[(size_t)(b * NN + n0) * 12 + i];
        it[2 * i] = u & 0xFFFF;
        it[2 * i + 1] = u >> 16;
    }
    __syncthreads();

    const unsigned int* Eb = Eph + ((size_t)(b * MM) << 7);
    for (int j2 = 0; j2 < 16; ++j2) {
        int j = 2 * j2 + rs;
        int n = n0 + j;
        const int* itj = &it[j * KNN];
        float al = 0.f, ah = 0.f, bl = 0.f, bh = 0.f;
        float cl = 0.f, ch = 0.f, dl = 0.f, dh = 0.f;
        #pragma unroll
        for (int k = 0; k < KNN; k += 4) {
            unsigned int u0 = Eb[((size_t)itj[k + 0] << 7) + cp];
            unsigned int u1 = Eb[((size_t)itj[k + 1] << 7) + cp];
            unsigned int u2 = Eb[((size_t)itj[k + 2] << 7) + cp];
            unsigned int u3 = Eb[((size_t)itj[k + 3] << 7) + cp];
            al += lo_bf(u0); ah += hi_bf(u0);
            bl += lo_bf(u1); bh += hi_bf(u1);
            cl += lo_bf(u2); ch += hi_bf(u2);
            dl += lo_bf(u3); dh += hi_bf(u3);
        }
        float2 xv = ((const float2*)(x + (((size_t)(b * NN + n)) << 8)))[cp];
        tile[j][2 * cp + 0] = xv.x + ((al + bl) + (cl + dl));
        tile[j][2 * cp + 1] = xv.y + ((ah + bh) + (ch + dh));
    }
    __syncthreads();

    float sum = 0.f, ss = 0.f;
    #pragma unroll 4
    for (int j = 0; j < 32; ++j) {
        float v = tile[j][tid];
        sum += v; ss += v * v;
    }
    bn1[(size_t)blk * 256 + tid] = sum;
    bn2[(size_t)blk * 256 + tid] = ss;

    for (int i = tid; i < CCH * 32; i += 256) {
        int c2 = i >> 5, j2 = i & 31;
        out[(((size_t)(b * CCH + c2)) << 14) + n0 + j2] = tile[j2][c2];
    }
}

// ---------------- K5: finalize BN stats -> a[c], bb[c] ----------------
__global__ __launch_bounds__(256) void k_stats(const float* __restrict__ bn1,
                                               const float* __restrict__ bn2,
                                               const float* __restrict__ gamma,
                                               const float* __restrict__ beta,
                                               float* __restrict__ ab) {
    __shared__ float r1[256], r2[256];
    int c = blockIdx.x;
    int t = threadIdx.x;
    float s1 = 0.f, s2 = 0.f;
    for (int i = t; i < 2048; i += 256) {
        s1 += bn1[i * 256 + c];
        s2 += bn2[i * 256 + c];
    }
    r1[t] = s1; r2[t] = s2;
    __syncthreads();
    for (int o = 128; o > 0; o >>= 1) {
        if (t < o) { r1[t] += r1[t + o]; r2[t] += r2[t + o]; }
        __syncthreads();
    }
    if (t == 0) {
        float mean = r1[0] * (1.0f / 65536.0f);
        float var  = r2[0] * (1.0f / 65536.0f) - mean * mean;
        float istd = rsqrtf(var + EPSV);
        float a = gamma[c] * istd;
        ab[c] = a;
        ab[CCH + c] = beta[c] - mean * a;
    }
}

// ---------------- K6: in-place normalize + SiLU ----------------
__global__ __launch_bounds__(256) void k_silu(float* __restrict__ out,
                                              const float* __restrict__ ab) {
    int i = blockIdx.x * 256 + threadIdx.x;     // float4 index, 4194304 total
    int c = (i >> 12) & 255;
    float a = ab[c], bb = ab[CCH + c];
    float4 v = ((float4*)out)[i];
    float t0 = a * v.x + bb;
    float t1 = a * v.y + bb;
    float t2 = a * v.z + bb;
    float t3 = a * v.w + bb;
    v.x = t0 / (1.0f + __expf(-t0));
    v.y = t1 / (1.0f + __expf(-t1));
    v.z = t2 / (1.0f + __expf(-t2));
    v.w = t3 / (1.0f + __expf(-t3));
    ((float4*)out)[i] = v;
}

extern "C" void kernel_launch(void* const* d_in, const int* in_sizes, int n_in,
                              void* d_out, int out_size, void* d_ws, size_t ws_size,
                              hipStream_t stream) {
    (void)in_sizes; (void)n_in; (void)out_size; (void)ws_size;
    const float* x       = (const float*)d_in[0];
    const float* coords  = (const float*)d_in[1];
    const float* anchors = (const float*)d_in[2];
    const float* fcw     = (const float*)d_in[3];
    const float* fcb     = (const float*)d_in[4];
    const float* gamma   = (const float*)d_in[5];
    const float* beta    = (const float*)d_in[6];
    float* out = (float*)d_out;

    // bf16-packed x lives in d_out (33.5 MB of 67 MB); dead before k_gather
    // overwrites d_out. ws footprint 18.1 MB (< proven-safe 19.2 MB).
    unsigned int* xh = (unsigned int*)d_out;

    char* ws = (char*)d_ws;
    ushort_t*     ws_idx   = (ushort_t*)    (ws + 0);          // 3,145,728 B
    int*          ws_deg   = (int*)         (ws + 3145728);    //     8,192 B
    int*          ws_offs  = (int*)         (ws + 3153920);    //     8,192 B
    ushort_t*     ws_list  = (ushort_t*)    (ws + 3162112);    // 3,145,728 B
    int*          ws_histT = (int*)         (ws + 6307840);    // 2,097,152 B
    int*          ws_posT  = (int*)         (ws + 8404992);    // 2,097,152 B
    unsigned int* ws_eph   = (unsigned int*)(ws + 10502144);   // 1,048,576 B
    float*        ws_S     = (float*)       (ws + 11550720);   // 2,097,152 B
    float*        ws_wt    = (float*)       (ws + 13647872);   //   262,144 B
    float*        ws_bn1   = (float*)       (ws + 13910016);   // 2,097,152 B
    float*        ws_bn2   = (float*)       (ws + 16007168);   // 2,097,152 B
    float*        ws_ab    = (float*)       (ws + 18104320);   //     2,048 B

    hipLaunchKernelGGL(k_cvt,     dim3(32768), dim3(256), 0, stream, x, xh);
    hipLaunchKernelGGL(k_wt,      dim3(256),   dim3(256), 0, stream, fcw, ws_wt);
    hipLaunchKernelGGL(k_topk,    dim3(1024),  dim3(256), 0, stream, coords, anchors, ws_idx, ws_histT);
    hipLaunchKernelGGL(k_scan,    dim3(2048),  dim3(64),  0, stream, ws_histT, ws_posT, ws_deg);
    hipLaunchKernelGGL(k_offsets, dim3(1),     dim3(256), 0, stream, ws_deg, ws_offs);
    hipLaunchKernelGGL(k_fill2,   dim3(1024),  dim3(256), 0, stream, (const unsigned int*)ws_idx, ws_posT, ws_offs, ws_list);
    hipLaunchKernelGGL(k_edge2a,  dim3(8192),  dim3(256), 0, stream, xh, ws_list, ws_offs, ws_deg, ws_S);
    hipLaunchKernelGGL(k_edge2b,  dim3(2048),  dim3(256), 0, stream, ws_S, ws_deg, ws_wt, fcb, ws_eph);
    hipLaunchKernelGGL(k_gather,  dim3(2048),  dim3(256), 0, stream, x, (const unsigned int*)ws_idx, ws_eph, out, ws_bn1, ws_bn2);
    hipLaunchKernelGGL(k_stats,   dim3(256),   dim3(256), 0, stream, ws_bn1, ws_bn2, gamma, beta, ws_ab);
    hipLaunchKernelGGL(k_silu,    dim3(16384), dim3(256), 0, stream, out, ws_ab);
}